// Round 16
// baseline (1185.337 us; speedup 1.0000x reference)
//
#include <hip/hip_runtime.h>
#include <hip/hip_bf16.h>

#define NTOK   8192
#define DMODEL 384
#define NHEAD  12
#define DHEAD  32
#define NLAYER 6
#define DFF    1536
#define SEQ    512
#define BATCH  16
#define WTAL   1916928L

typedef __attribute__((ext_vector_type(8))) short short8;
typedef __attribute__((ext_vector_type(4))) float f32x4;

__device__ __forceinline__ float sigmoidf_(float x){ return 1.f/(1.f+expf(-x)); }

__device__ __forceinline__ ushort f2b(float x){
  uint b = __builtin_bit_cast(uint, x);
  uint r = (b + 0x7FFFu + ((b>>16)&1u)) >> 16;
  return (ushort)r;
}
__device__ __forceinline__ uint pk2(float lo, float hi){
  return (uint)f2b(lo) | ((uint)f2b(hi)<<16);
}
// 4 bf16 (packed uint2) -> float4
__device__ __forceinline__ float4 b2f4(uint2 u){
  float4 f;
  f.x = __builtin_bit_cast(float, u.x<<16);
  f.y = __builtin_bit_cast(float, u.x & 0xffff0000u);
  f.z = __builtin_bit_cast(float, u.y<<16);
  f.w = __builtin_bit_cast(float, u.y & 0xffff0000u);
  return f;
}
// 8-lane sum (aligned 8-group): quad xor1, quad xor2, row_half_mirror
__device__ __forceinline__ float red8(float x){
  int t = __builtin_amdgcn_update_dpp(0, __builtin_bit_cast(int,x), 0xB1, 0xF, 0xF, true);
  x += __builtin_bit_cast(float,t);
  t = __builtin_amdgcn_update_dpp(0, __builtin_bit_cast(int,x), 0x4E, 0xF, 0xF, true);
  x += __builtin_bit_cast(float,t);
  t = __builtin_amdgcn_update_dpp(0, __builtin_bit_cast(int,x), 0x141, 0xF, 0xF, true);
  x += __builtin_bit_cast(float,t);
  return x;
}
__device__ __forceinline__ void gload16(const ushort* g, ushort* l){
  __builtin_amdgcn_global_load_lds((const __attribute__((address_space(1))) void*)g,
                                   (__attribute__((address_space(3))) void*)l, 16, 0, 0);
}

// ---------------- shared beta helper (128-thread LN blocks) ----------------
__device__ __forceinline__ void beta_from_row(
    int n, int tid, const float y0, const float y1, const float y2,
    const float* __restrict__ Wb, const float* __restrict__ bbv,
    const int* __restrict__ amask, float* __restrict__ Bb,
    float (*bred)[13])
{
  float part[12];
  #pragma unroll
  for (int hh=0;hh<12;hh++) part[hh]=0.f;
  #pragma unroll
  for (int j=0;j<3;j++){
    int d = tid + j*128;
    float yv = (j==0)?y0:(j==1)?y1:y2;
    const float* wrow = Wb + (long)d*12;
    #pragma unroll
    for (int hh=0;hh<12;hh++) part[hh] += yv * wrow[hh];
  }
  #pragma unroll
  for (int hh=0;hh<12;hh++) bred[tid][hh] = part[hh];
  __syncthreads();
  if (tid < 96){
    int hh = tid>>3, i = tid&7;
    float s = 0.f;
    #pragma unroll
    for (int k=0;k<16;k++) s += bred[i + 8*k][hh];
    s += __shfl_xor(s,1); s += __shfl_xor(s,2); s += __shfl_xor(s,4);
    if (i==0) Bb[(long)n*NHEAD+hh] = (float)amask[n] * sigmoidf_(s + bbv[hh]);
  }
}

// ---------------- embedding + LN (f32 + bf16 shadow) + beta(layer 0) -------------
__global__ __launch_bounds__(128) void embed_ln_kernel(
    const int* __restrict__ ids, const float* __restrict__ tok,
    const float* __restrict__ pos, const float* __restrict__ typ,
    const float* __restrict__ g, const float* __restrict__ bvec,
    float* __restrict__ out, ushort* __restrict__ outb,
    const float* __restrict__ Wb0, const float* __restrict__ bb0,
    const int* __restrict__ amask, float* __restrict__ Bb)
{
  __shared__ float r1[2], r2[2];
  __shared__ float bred[128][13];
  int n = blockIdx.x;
  int t = n & (SEQ-1);
  int id = ids[n];
  int tid = threadIdx.x;
  float v[3]; float s1=0.f, s2=0.f;
  #pragma unroll
  for (int j=0;j<3;j++){
    int d = tid + j*128;
    float x = tok[(long)id*DMODEL + d] + pos[t*DMODEL + d] + typ[d];
    v[j]=x; s1+=x; s2+=x*x;
  }
  #pragma unroll
  for (int m=1;m<64;m<<=1){ s1 += __shfl_xor(s1,m); s2 += __shfl_xor(s2,m); }
  if ((tid&63)==0){ r1[tid>>6]=s1; r2[tid>>6]=s2; }
  __syncthreads();
  s1 = r1[0]+r1[1]; s2 = r2[0]+r2[1];
  float mean = s1*(1.f/DMODEL);
  float var  = s2*(1.f/DMODEL) - mean*mean;
  float inv  = rsqrtf(var + 1e-12f);
  float y[3];
  #pragma unroll
  for (int j=0;j<3;j++){
    int d = tid + j*128;
    y[j] = (v[j]-mean)*inv*g[d] + bvec[d];
    out[(long)n*DMODEL + d] = y[j];
    outb[(long)n*DMODEL + d] = f2b(y[j]);
  }
  __syncthreads();
  beta_from_row(n, tid, y[0], y[1], y[2], Wb0, bb0, amask, Bb, bred);
}

// ---------------- residual add + LN (f32 + bf16 shadow) + optional beta ----------
__global__ __launch_bounds__(128) void add_ln_kernel(
    float* __restrict__ h, const float* __restrict__ res,
    const float* __restrict__ g, const float* __restrict__ bvec,
    ushort* __restrict__ hb,
    const float* __restrict__ Wbn, const float* __restrict__ bbn,
    const int* __restrict__ amask, float* __restrict__ Bb)
{
  __shared__ float r1[2], r2[2];
  __shared__ float bred[128][13];
  int n = blockIdx.x;
  int tid = threadIdx.x;
  float v[3]; float s1=0.f, s2=0.f;
  #pragma unroll
  for (int j=0;j<3;j++){
    int d = tid + j*128;
    float x = h[(long)n*DMODEL + d] + res[(long)n*DMODEL + d];
    v[j]=x; s1+=x; s2+=x*x;
  }
  #pragma unroll
  for (int m=1;m<64;m<<=1){ s1 += __shfl_xor(s1,m); s2 += __shfl_xor(s2,m); }
  if ((tid&63)==0){ r1[tid>>6]=s1; r2[tid>>6]=s2; }
  __syncthreads();
  s1 = r1[0]+r1[1]; s2 = r2[0]+r2[1];
  float mean = s1*(1.f/DMODEL);
  float var  = s2*(1.f/DMODEL) - mean*mean;
  float inv  = rsqrtf(var + 1e-12f);
  float y[3];
  #pragma unroll
  for (int j=0;j<3;j++){
    int d = tid + j*128;
    y[j] = (v[j]-mean)*inv*g[d] + bvec[d];
    h[(long)n*DMODEL + d] = y[j];
    hb[(long)n*DMODEL + d] = f2b(y[j]);
  }
  if (Wbn){
    __syncthreads();
    beta_from_row(n, tid, y[0], y[1], y[2], Wbn, bbn, amask, Bb, bred);
  }
}

// ---------------- ALL-layer weight transpose+convert (runs once) ----------------
__global__ __launch_bounds__(256) void tcvt6(
    const float* __restrict__ Wq, const float* __restrict__ Wk,
    const float* __restrict__ Wv, const float* __restrict__ Wg,
    const float* __restrict__ Wo, const float* __restrict__ W1,
    const float* __restrict__ W2, ushort* __restrict__ WTA)
{
  __shared__ float tile[32][33];
  int l = blockIdx.x / 1872;
  int bid = blockIdx.x % 1872;
  const float* Wq_l = Wq + (long)l*DMODEL*DMODEL;
  const float* Wk_l = Wk + (long)l*DMODEL*DMODEL;
  const float* Wv_l = Wv + (long)l*DMODEL*DMODEL;
  const float* Wg_l = Wg + (long)l*DMODEL*DMODEL;
  const float* Wo_l = Wo + (long)l*DMODEL*DMODEL;
  const float* W1_l = W1 + (long)l*DMODEL*DFF;
  const float* W2_l = W2 + (long)l*DFF*DMODEL;
  ushort* WTAl = WTA + (long)l*WTAL;

  const float* src; long dstbase; int rowlen, Nd, tk, tn, row0;
  if (bid < 720){
    int seg = bid/144, t = bid%144;
    tk = t%12; tn = t/12;
    src = (seg==0)?Wq_l:(seg==1)?Wk_l:(seg==2)?Wv_l:(seg==3)?Wg_l:Wo_l;
    Nd = 384; rowlen = 384;
    if (seg<4){ dstbase=0; row0=seg*384; }
    else      { dstbase=589824; row0=0; }
  } else if (bid < 1296){
    int t = bid-720; tk=t%12; tn=t/12;
    src=W1_l; Nd=DFF; dstbase=737280; row0=0; rowlen=384;
  } else {
    int t = bid-1296; tk=t%48; tn=t/48;
    src=W2_l; Nd=384; dstbase=1327104; row0=0; rowlen=DFF;
  }
  int k0=tk*32, n0=tn*32;
  int tt=threadIdx.x;
  int r=tt>>3, c4=(tt&7)<<2;
  const float* sp = src + (long)(k0+r)*Nd + n0 + c4;
  float4 f = *(const float4*)sp;
  tile[r][c4+0]=f.x; tile[r][c4+1]=f.y; tile[r][c4+2]=f.z; tile[r][c4+3]=f.w;
  __syncthreads();
  ushort4 o;
  o.x=f2b(tile[c4+0][r]); o.y=f2b(tile[c4+1][r]);
  o.z=f2b(tile[c4+2][r]); o.w=f2b(tile[c4+3][r]);
  *(ushort4*)(WTAl + dstbase + (long)(row0+n0+r)*rowlen + k0 + c4) = o;
}

// XCD-aware swizzle: grid (64, ny), total %8==0. Returns (bx,by).
__device__ __forceinline__ int2 xcd_swz(){
  int lin = blockIdx.y*64 + blockIdx.x;
  int nb = gridDim.x*gridDim.y;
  int s = (lin & 7)*(nb>>3) + (lin>>3);
  return make_int2(s & 63, s >> 6);
}

// ---------------- bf16 MFMA GEMM, 128x128 tile, BK=32, 2-phase dbuf -------------
// T3 minimal 2-phase (learn_hip m248): dbuf LDS, stage next tile between ds_read
// and MFMA, single counted-drain vmcnt(0)+s_barrier AFTER the MFMAs.
template<int ACT, int OUTBF>
__global__ __launch_bounds__(256) void gemm_bf(
    const ushort* __restrict__ Xb, const ushort* __restrict__ WT,
    const float* __restrict__ bias, void* __restrict__ Cv, int Kd, int Nd)
{
  __shared__ ushort A0[128*32], A1[128*32], B0[128*32], B1[128*32];
  int tid = threadIdx.x;
  int2 bxy = xcd_swz();
  int bm = bxy.x*128, bn = bxy.y*128;
  int w = tid>>6, lane = tid&63;
  int wm = w>>1, wn = w&1;
  f32x4 acc[4][4];
  #pragma unroll
  for (int i=0;i<4;i++)
    #pragma unroll
    for (int j=0;j<4;j++) acc[i][j]=(f32x4)(0.f);

  int cl = lane&15, koff = (lane>>4)*8;
  int srow = w*32 + (lane>>2);
  int scol = (lane&3)*8;
  const ushort* gA0p = Xb + (long)(bm+srow)*Kd + scol;
  const ushort* gA1p = gA0p + 16*(long)Kd;
  const ushort* gB0p = WT + (long)(bn+srow)*Kd + scol;
  const ushort* gB1p = gB0p + 16*(long)Kd;
  int lofA = w*1024, lofB = w*1024;
  int NI = Kd >> 5;

  // prologue: stage tile 0 into buf0
  gload16(gA0p, A0+lofA); gload16(gA1p, A0+lofA+512);
  gload16(gB0p, B0+lofB); gload16(gB1p, B0+lofB+512);
  asm volatile("s_waitcnt vmcnt(0)" ::: "memory");
  __builtin_amdgcn_s_barrier();

  for (int it=0; it<NI; it+=2){
    { // body A: compute buf0, stage tile it+1 -> buf1
      short8 bfr[4], afr[4];
      #pragma unroll
      for (int ni=0;ni<4;ni++) bfr[ni] = *(const short8*)&B0[(wn*64+ni*16+cl)*32 + koff];
      #pragma unroll
      for (int mi=0;mi<4;mi++) afr[mi] = *(const short8*)&A0[(wm*64+mi*16+cl)*32 + koff];
      int k0 = (it+1)<<5;
      gload16(gA0p+k0, A1+lofA); gload16(gA1p+k0, A1+lofA+512);
      gload16(gB0p+k0, B1+lofB); gload16(gB1p+k0, B1+lofB+512);
      #pragma unroll
      for (int mi=0;mi<4;mi++)
        #pragma unroll
        for (int ni=0;ni<4;ni++)
          acc[mi][ni] = __builtin_amdgcn_mfma_f32_16x16x32_bf16(afr[mi], bfr[ni], acc[mi][ni], 0,0,0);
      asm volatile("s_waitcnt vmcnt(0)" ::: "memory");
      __builtin_amdgcn_s_barrier();
    }
    { // body B: compute buf1, stage tile it+2 -> buf0
      short8 bfr[4], afr[4];
      #pragma unroll
      for (int ni=0;ni<4;ni++) bfr[ni] = *(const short8*)&B1[(wn*64+ni*16+cl)*32 + koff];
      #pragma unroll
      for (int mi=0;mi<4;mi++) afr[mi] = *(const short8*)&A1[(wm*64+mi*16+cl)*32 + koff];
      if (it+2 < NI){
        int k0 = (it+2)<<5;
        gload16(gA0p+k0, A0+lofA); gload16(gA1p+k0, A0+lofA+512);
        gload16(gB0p+k0, B0+lofB); gload16(gB1p+k0, B0+lofB+512);
      }
      #pragma unroll
      for (int mi=0;mi<4;mi++)
        #pragma unroll
        for (int ni=0;ni<4;ni++)
          acc[mi][ni] = __builtin_amdgcn_mfma_f32_16x16x32_bf16(afr[mi], bfr[ni], acc[mi][ni], 0,0,0);
      if (it+2 < NI){
        asm volatile("s_waitcnt vmcnt(0)" ::: "memory");
        __builtin_amdgcn_s_barrier();
      }
    }
  }

  int rb = (lane>>4)*4;
  #pragma unroll
  for (int ni=0; ni<4; ni++){
    int col = bn + wn*64 + ni*16 + cl;
    float bsv = bias ? bias[col] : 0.f;
    #pragma unroll
    for (int mi=0; mi<4; mi++){
      #pragma unroll
      for (int j=0;j<4;j++){
        int row = bm + wm*64 + mi*16 + rb + j;
        float c = acc[mi][ni][j] + bsv;
        if (ACT==1)      c = c*sigmoidf_(c);
        else if (ACT==2) c = 0.5f*c*(1.f+erff(c*0.70710678118f));
        else if (ACT==3) c = sigmoidf_(c);
        if (OUTBF) ((ushort*)Cv)[(long)row*Nd + col] = f2b(c);
        else       ((float*)Cv)[(long)row*Nd + col] = c;
      }
    }
  }
}

// ---------------- bf16 MFMA GEMM, 128x64 tile, BK=32, 2-phase dbuf ----------------
template<int ACT, int OUTBF>
__global__ __launch_bounds__(256) void gemm_bf2(
    const ushort* __restrict__ Xb, const ushort* __restrict__ WT,
    const float* __restrict__ bias, void* __restrict__ Cv, int Kd, int Nd)
{
  __shared__ ushort A0[128*32], A1[128*32], B0[64*32], B1[64*32];
  int tid = threadIdx.x;
  int2 bxy = xcd_swz();
  int bm = bxy.x*128, bn = bxy.y*64;
  int w = tid>>6, lane = tid&63;
  int wm = w>>1, wn = w&1;
  f32x4 acc[4][2];
  #pragma unroll
  for (int i=0;i<4;i++){ acc[i][0]=(f32x4)(0.f); acc[i][1]=(f32x4)(0.f); }

  int cl = lane&15, koff = (lane>>4)*8;
  int srowA = w*32 + (lane>>2);
  int scol = (lane&3)*8;
  const ushort* gA0p = Xb + (long)(bm+srowA)*Kd + scol;
  const ushort* gA1p = gA0p + 16*(long)Kd;
  int srowB = w*16 + (lane>>2);
  const ushort* gBp = WT + (long)(bn+srowB)*Kd + scol;
  int lofA = w*1024, lofB = w*512;
  int NI = Kd >> 5;

  gload16(gA0p, A0+lofA); gload16(gA1p, A0+lofA+512); gload16(gBp, B0+lofB);
  asm volatile("s_waitcnt vmcnt(0)" ::: "memory");
  __builtin_amdgcn_s_barrier();

  for (int it=0; it<NI; it+=2){
    { // body A
      short8 b0r = *(const short8*)&B0[(wn*32+cl)*32 + koff];
      short8 b1r = *(const short8*)&B0[(wn*32+16+cl)*32 + koff];
      short8 afr[4];
      #pragma unroll
      for (int mi=0;mi<4;mi++) afr[mi] = *(const short8*)&A0[(wm*64+mi*16+cl)*32 + koff];
      int k0 = (it+1)<<5;
      gload16(gA0p+k0, A1+lofA); gload16(gA1p+k0, A1+lofA+512); gload16(gBp+k0, B1+lofB);
      #pragma unroll
      for (int mi=0;mi<4;mi++){
        acc[mi][0] = __builtin_amdgcn_mfma_f32_16x16x32_bf16(afr[mi], b0r, acc[mi][0], 0,0,0);
        acc[mi][1] = __builtin_amdgcn_mfma_f32_16x16x32_bf16(afr[mi], b1r, acc[mi][1], 0,0,0);
      }
      asm volatile("s_waitcnt vmcnt(0)" ::: "memory");
      __builtin_amdgcn_s_barrier();
    }
    { // body B
      short8 b0r = *(const short8*)&B1[(wn*32+cl)*32 + koff];
      short8 b1r = *(const short8*)&B1[(wn*32+16+cl)*32 + koff];
      short8 afr[4];
      #pragma unroll
      for (int mi=0;mi<4;mi++) afr[mi] = *(const short8*)&A1[(wm*64+mi*16+cl)*32 + koff];
      if (it+2 < NI){
        int k0 = (it+2)<<5;
        gload16(gA0p+k0, A0+lofA); gload16(gA1p+k0, A0+lofA+512); gload16(gBp+k0, B0+lofB);
      }
      #pragma unroll
      for (int mi=0;mi<4;mi++){
        acc[mi][0] = __builtin_amdgcn_mfma_f32_16x16x32_bf16(afr[mi], b0r, acc[mi][0], 0,0,0);
        acc[mi][1] = __builtin_amdgcn_mfma_f32_16x16x32_bf16(afr[mi], b1r, acc[mi][1], 0,0,0);
      }
      if (it+2 < NI){
        asm volatile("s_waitcnt vmcnt(0)" ::: "memory");
        __builtin_amdgcn_s_barrier();
      }
    }
  }

  int rb = (lane>>4)*4;
  #pragma unroll
  for (int ni=0; ni<2; ni++){
    int col = bn + wn*32 + ni*16 + cl;
    float bsv = bias ? bias[col] : 0.f;
    #pragma unroll
    for (int mi=0; mi<4; mi++){
      #pragma unroll
      for (int j=0;j<4;j++){
        int row = bm + wm*64 + mi*16 + rb + j;
        float c = acc[mi][ni][j] + bsv;
        if (ACT==1)      c = c*sigmoidf_(c);
        else if (ACT==2) c = 0.5f*c*(1.f+erff(c*0.70710678118f));
        else if (ACT==3) c = sigmoidf_(c);
        if (OUTBF) ((ushort*)Cv)[(long)row*Nd + col] = f2b(c);
        else       ((float*)Cv)[(long)row*Nd + col] = c;
      }
    }
  }
}

// ---------------- fused QKVG GEMM, BK=32, 2-phase dbuf, bf16 output ----------------
__global__ __launch_bounds__(256) void gemm_qkvg(
    const ushort* __restrict__ Xb, const ushort* __restrict__ WT,
    const float* __restrict__ bq, const float* __restrict__ bk,
    const float* __restrict__ bv, ushort* __restrict__ C)
{
  __shared__ ushort A0[128*32], A1[128*32], B0[128*32], B1[128*32];
  int tid = threadIdx.x;
  int2 bxy = xcd_swz();
  int bm = bxy.x*128, bn = bxy.y*128;
  int w = tid>>6, lane = tid&63;
  int wm = w>>1, wn = w&1;
  f32x4 acc[4][4];
  #pragma unroll
  for (int i=0;i<4;i++)
    #pragma unroll
    for (int j=0;j<4;j++) acc[i][j]=(f32x4)(0.f);

  int cl = lane&15, koff = (lane>>4)*8;
  int srow = w*32 + (lane>>2);
  int scol = (lane&3)*8;
  const ushort* gA0p = Xb + (long)(bm+srow)*DMODEL + scol;
  const ushort* gA1p = gA0p + 16*DMODEL;
  const ushort* gB0p = WT + (long)(bn+srow)*DMODEL + scol;
  const ushort* gB1p = gB0p + 16*DMODEL;
  int lofA = w*1024, lofB = w*1024;
  const int NI = DMODEL >> 5;   // 12

  gload16(gA0p, A0+lofA); gload16(gA1p, A0+lofA+512);
  gload16(gB0p, B0+lofB); gload16(gB1p, B0+lofB+512);
  asm volatile("s_waitcnt vmcnt(0)" ::: "memory");
  __builtin_amdgcn_s_barrier();

  for (int it=0; it<NI; it+=2){
    { // body A
      short8 bfr[4], afr[4];
      #pragma unroll
      for (int ni=0;ni<4;ni++) bfr[ni] = *(const short8*)&B0[(wn*64+ni*16+cl)*32 + koff];
      #pragma unroll
      for (int mi=0;mi<4;mi++) afr[mi] = *(const short8*)&A0[(wm*64+mi*16+cl)*32 + koff];
      int k0 = (it+1)<<5;
      gload16(gA0p+k0, A1+lofA); gload16(gA1p+k0, A1+lofA+512);
      gload16(gB0p+k0, B1+lofB); gload16(gB1p+k0, B1+lofB+512);
      #pragma unroll
      for (int mi=0;mi<4;mi++)
        #pragma unroll
        for (int ni=0;ni<4;ni++)
          acc[mi][ni] = __builtin_amdgcn_mfma_f32_16x16x32_bf16(afr[mi], bfr[ni], acc[mi][ni], 0,0,0);
      asm volatile("s_waitcnt vmcnt(0)" ::: "memory");
      __builtin_amdgcn_s_barrier();
    }
    { // body B
      short8 bfr[4], afr[4];
      #pragma unroll
      for (int ni=0;ni<4;ni++) bfr[ni] = *(const short8*)&B1[(wn*64+ni*16+cl)*32 + koff];
      #pragma unroll
      for (int mi=0;mi<4;mi++) afr[mi] = *(const short8*)&A1[(wm*64+mi*16+cl)*32 + koff];
      if (it+2 < NI){
        int k0 = (it+2)<<5;
        gload16(gA0p+k0, A0+lofA); gload16(gA1p+k0, A0+lofA+512);
        gload16(gB0p+k0, B0+lofB); gload16(gB1p+k0, B0+lofB+512);
      }
      #pragma unroll
      for (int mi=0;mi<4;mi++)
        #pragma unroll
        for (int ni=0;ni<4;ni++)
          acc[mi][ni] = __builtin_amdgcn_mfma_f32_16x16x32_bf16(afr[mi], bfr[ni], acc[mi][ni], 0,0,0);
      if (it+2 < NI){
        asm volatile("s_waitcnt vmcnt(0)" ::: "memory");
        __builtin_amdgcn_s_barrier();
      }
    }
  }

  int seg = bxy.y/3;
  const float* bp = (seg==0)?bq:(seg==1)?bk:(seg==2)?bv:nullptr;
  int boff = seg*384;
  int rb = (lane>>4)*4;
  #pragma unroll
  for (int ni=0; ni<4; ni++){
    int col = bn + wn*64 + ni*16 + cl;
    float bsv = bp ? bp[col-boff] : 0.f;
    #pragma unroll
    for (int mi=0; mi<4; mi++){
      #pragma unroll
      for (int j=0;j<4;j++){
        int row = bm + wm*64 + mi*16 + rb + j;
        float c = acc[mi][ni][j] + bsv;
        if (seg<2)       c = c*sigmoidf_(c);
        else if (seg==3) c = sigmoidf_(c);
        C[(long)row*DFF + col] = f2b(c);
      }
    }
  }
}

// ---------------- delta-rule scan v12 (round-13/15 winner): 512 thr, f32 LDS ----------
__global__ __launch_bounds__(512,2) void scan12_kernel(
    const ushort* __restrict__ QKVGb, const float* __restrict__ Bb,
    const float* __restrict__ dfl, const float* __restrict__ dsl,
    const float* __restrict__ mixl, ushort* __restrict__ OA)
{
  __shared__ float Qc[66][36], Kc[66][36], Vt[32][68], Bc[68], Ofs[2][64][36];
  int bh = blockIdx.x;
  int b = bh / NHEAD, hh = bh - b*NHEAD;
  int tid = threadIdx.x;
  int w = tid>>6, lane = tid&63;
  int st = w>>2, vq = w&3;
  int kq = lane&7, v = vq*8 + (lane>>3);
  float dec = sigmoidf_(st ? dsl[hh] : dfl[hh]);
  float mix = sigmoidf_(mixl[hh]);
  long rowbase = (long)b*SEQ;
  const ushort* rp = QKVGb + rowbase*DFF + hh*32;
  const float* bp = Bb + rowbase*NHEAD + hh;

  int r0 = tid>>3, c40 = (tid&7)<<2;
  float S[4] = {0.f,0.f,0.f,0.f};

  float4 sq, sk, sv; float sb = 0.f;
  {
    long g = (long)r0*DFF;
    sq = b2f4(*(const uint2*)(rp + g + c40));
    sk = b2f4(*(const uint2*)(rp + g + 384 + c40));
    sv = b2f4(*(const uint2*)(rp + g + 768 + c40));
    if (tid < 64) sb = bp[(long)tid*NHEAD];
    float ss = red8(sk.x*sk.x + sk.y*sk.y + sk.z*sk.z + sk.w*sk.w);
    float inv = 1.f/(sqrtf(ss)+1e-6f);
    sk.x*=inv; sk.y*=inv; sk.z*=inv; sk.w*=inv;
    *(float4*)&Qc[r0][c40] = sq;
    *(float4*)&Kc[r0][c40] = sk;
    Vt[c40+0][r0]=sv.x; Vt[c40+1][r0]=sv.y; Vt[c40+2][r0]=sv.z; Vt[c40+3][r0]=sv.w;
    if (tid < 64) Bc[tid] = sb;
  }
  __syncthreads();

  for (int c=0; c<8; ++c){
    if (c < 7){
      long g = (long)((c+1)*64 + r0)*DFF;
      sq = b2f4(*(const uint2*)(rp + g + c40));
      sk = b2f4(*(const uint2*)(rp + g + 384 + c40));
      sv = b2f4(*(const uint2*)(rp + g + 768 + c40));
      if (tid < 64) sb = bp[(long)((c+1)*64 + tid)*NHEAD];
    }
    float4 g4 = b2f4(*(const uint2*)(rp + (long)(c*64 + r0)*DFF + 1152 + c40));
    __builtin_amdgcn_sched_barrier(0);

    float4 kA = *(const float4*)&Kc[0][kq*4];
    float4 qA = *(const float4*)&Qc[0][kq*4];
    float4 kB = *(const float4*)&Kc[1][kq*4];
    float4 qB = *(const float4*)&Qc[1][kq*4];
    float vrA[4], brA[4], vrB[4], brB[4];
    *(float4*)vrA = *(const float4*)&Vt[v][0];
    *(float4*)brA = *(const float4*)&Bc[0];

    for (int t8=0; t8<8; ++t8){
      *(float4*)vrB = *(const float4*)&Vt[v][(2*t8+1)*4];
      *(float4*)brB = *(const float4*)&Bc[(2*t8+1)*4];
      #pragma unroll
      for (int i=0;i<4;i++){
        int t = t8*8 + i;
        float4 kN = *(const float4*)&Kc[t+2][kq*4];
        float4 qN = *(const float4*)&Qc[t+2][kq*4];
        float pa = kA.x*S[0] + kA.y*S[1];
        float pb = kA.z*S[2] + kA.w*S[3];
        float p = red8(pa+pb);
        float err = (vrA[i] - p)*brA[i];
        S[0] = dec*S[0] + kA.x*err;
        S[1] = dec*S[1] + kA.y*err;
        S[2] = dec*S[2] + kA.z*err;
        S[3] = dec*S[3] + kA.w*err;
        float oa = qA.x*S[0] + qA.y*S[1];
        float ob = qA.z*S[2] + qA.w*S[3];
        float o = red8(oa+ob);
        if (kq==0) Ofs[st][t][v] = o;
        kA=kB; qA=qB; kB=kN; qB=qN;
      }
      *(float4*)vrA = *(const float4*)&Vt[v][(2*t8+2)*4];
      *(float4*)brA = *(const float4*)&Bc[(2*t8+2)*4];
      #pragma unroll
      for (int i=0;i<4;i++){
        int t = t8*8 + 4 + i;
        float4 kN = *(const float4*)&Kc[t+2][kq*4];   // rows 64/65 = pad
        float4 qN = *(const float4*)&Qc[t+2][kq*4];
        float pa = kA.x*S[0] + kA.y*S[1];
        float pb = kA.z*S[2] + kA.w*S[3];
        float p = red8(pa+pb);
        float err = (vrB[i] - p)*brB[i];
        S[0] = dec*S[0] + kA.x*err;
        S[1] = dec*S[1] + kA.y*err;
        S[2] = dec*S[2] + kA.z*err;
        S[3] = dec*S[3] + kA.w*err;
        float oa = qA.x*S[0] + qA.y*S[1];
        float ob = qA.z*S[2] + qA.w*S[3];
        float o = red8(oa+ob);
        if (kq==0) Ofs[st][t][v] = o;
        kA=kB; qA=qB; kB=kN; qB=qN;
      }
    }
    __syncthreads();

    {
      float4 of = *(const float4*)&Ofs[0][r0][c40];
      float4 os = *(const float4*)&Ofs[1][r0][c40];
      float a0 = (mix*of.x + (1.f-mix)*os.x)*g4.x;
      float a1 = (mix*of.y + (1.f-mix)*os.y)*g4.y;
      float a2 = (mix*of.z + (1.f-mix)*os.z)*g4.z;
      float a3 = (mix*of.w + (1.f-mix)*os.w)*g4.w;
      uint2 o2; o2.x = pk2(a0,a1); o2.y = pk2(a2,a3);
      *(uint2*)(OA + (rowbase + c*64 + r0)*DMODEL + hh*32 + c40) = o2;
    }
    if (c < 7){
      *(float4*)&Qc[r0][c40] = sq;
      *(float4*)&Kc[r0][c40] = sk;
      Vt[c40+0][r0]=sv.x; Vt[c40+1][r0]=sv.y; Vt[c40+2][r0]=sv.z; Vt[c40+3][r0]=sv.w;
      if (tid < 64) Bc[tid] = sb;
    }
    __syncthreads();
  }
}

// ---------------- masked mean pool + L2 normalize ----------------
__global__ __launch_bounds__(384) void pool_norm_kernel(
    const float* __restrict__ h, const int* __restrict__ mask, float* __restrict__ out)
{
  int b = blockIdx.x; int d = threadIdx.x;
  float s=0.f, ms=0.f;
  for (int t=0;t<SEQ;t++){
    float m = (float)mask[b*SEQ+t];
    s += h[((long)b*SEQ+t)*DMODEL + d]*m;
    ms += m;
  }
  float emb = s / fmaxf(ms, 1e-9f);
  float ss = emb*emb;
  #pragma unroll
  for (int m2=1;m2<64;m2<<=1) ss += __shfl_xor(ss,m2);
  __shared__ float r[6];
  if ((d&63)==0) r[d>>6]=ss;
  __syncthreads();
  ss = r[0]+r[1]+r[2]+r[3]+r[4]+r[5];
  out[b*DMODEL+d] = emb / (sqrtf(ss)+1e-12f);
}

extern "C" void kernel_launch(void* const* d_in, const int* in_sizes, int n_in,
                              void* d_out, int out_size, void* d_ws, size_t ws_size,
                              hipStream_t stream)
{
  const int*   ids   = (const int*)d_in[0];
  const int*   amask = (const int*)d_in[1];
  const float* etok  = (const float*)d_in[2];
  const float* epos  = (const float*)d_in[3];
  const float* etyp  = (const float*)d_in[4];
  const float* elng  = (const float*)d_in[5];
  const float* elnb  = (const float*)d_in[6];
  const float* Wq = (const float*)d_in[7];  const float* bq = (const float*)d_in[8];
  const float* Wk = (const float*)d_in[9];  const float* bk = (const float*)d_in[10];
  const float* Wv = (const float*)d_in[11]; const float* bv = (const float*)d_in[12];
  const float* Wb = (const float*)d_in[13]; const float* bb = (const float*)d_in[14];
  const float* dfl = (const float*)d_in[15];
  const float* dsl = (const float*)d_in[16];
  const float* mixl= (const float*)d_in[17];
  const float* Wg = (const float*)d_in[18];
  const float* Wo = (const float*)d_in[19]; const float* bo = (const float*)d_in[20];
  const float* alng = (const float*)d_in[21]; const float* alnb = (const float*)d_in[22];
  const float* W1 = (const float*)d_in[23]; const float* b1 = (const float*)d_in[24];
  const float* W2 = (const float*)d_in[25]; const float* b2 = (const float*)d_in[26];
  const float* flng = (const float*)d_in[27]; const float* flnb = (const float*)d_in[28];

  float* ws = (float*)d_ws;
  const long TD = (long)NTOK*DMODEL;
  float* h      = ws;                              // [8192][384] f32
  ushort* hbf   = (ushort*)(h + TD);               // [8192][384] bf16
  ushort* QKVGb = (ushort*)(h + TD + TD/2);        // [8192][1536] bf16 (2*TD floats)
  ushort* OA    = (ushort*)(h + TD + TD/2 + 2*TD); // [8192][384] bf16
  float* Rb     = h + TD + TD/2 + 2*TD + TD/2;     // attn/ffn output f32
  float* Bb     = Rb + TD;                         // [8192][12]
  ushort* WTA   = (ushort*)(Bb + (long)NTOK*NHEAD);// 6 layers x WTAL ushorts
  ushort* F1B   = QKVGb;                           // FFN mid bf16, aliases dead QKVGb

  embed_ln_kernel<<<NTOK,128,0,stream>>>(ids, etok, epos, etyp, elng, elnb, h, hbf,
                                         Wb, bb, amask, Bb);
  tcvt6<<<6*1872,256,0,stream>>>(Wq, Wk, Wv, Wg, Wo, W1, W2, WTA);

  for (int l=0;l<NLAYER;l++){
    ushort* WTAl = WTA + (long)l*WTAL;
    gemm_qkvg<<<dim3(64,12),256,0,stream>>>(hbf, WTAl, bq+l*DMODEL, bk+l*DMODEL, bv+l*DMODEL, QKVGb);
    scan12_kernel<<<BATCH*NHEAD,512,0,stream>>>(QKVGb, Bb, dfl + l*NHEAD, dsl + l*NHEAD, mixl + l*NHEAD, OA);
    gemm_bf2<0,0><<<dim3(64,6),256,0,stream>>>(OA, WTAl+589824, bo + l*DMODEL, Rb, DMODEL, DMODEL);
    add_ln_kernel<<<NTOK,128,0,stream>>>(h, Rb, alng + (long)l*DMODEL, alnb + (long)l*DMODEL, hbf,
                                         nullptr, nullptr, amask, Bb);
    gemm_bf<2,1><<<dim3(64,12),256,0,stream>>>(hbf, WTAl+737280, b1 + (long)l*DFF, F1B, DMODEL, DFF);
    gemm_bf2<0,0><<<dim3(64,6),256,0,stream>>>(F1B, WTAl+1327104, b2 + (long)l*DMODEL, Rb, DFF, DMODEL);
    const float* Wbn = (l+1<NLAYER) ? (Wb + (long)(l+1)*DMODEL*NHEAD) : nullptr;
    const float* bbn = (l+1<NLAYER) ? (bb + (long)(l+1)*NHEAD) : nullptr;
    add_ln_kernel<<<NTOK,128,0,stream>>>(h, Rb, flng + (long)l*DMODEL, flnb + (long)l*DMODEL, hbf,
                                         Wbn, bbn, amask, Bb);
  }

  pool_norm_kernel<<<BATCH,384,0,stream>>>(h, amask, (float*)d_out);
}

// Round 17
// 1145.164 us; speedup vs baseline: 1.0351x; 1.0351x over previous
//
#include <hip/hip_runtime.h>
#include <hip/hip_bf16.h>

#define NTOK   8192
#define DMODEL 384
#define NHEAD  12
#define DHEAD  32
#define NLAYER 6
#define DFF    1536
#define SEQ    512
#define BATCH  16
#define WTAL   1916928L

typedef __attribute__((ext_vector_type(8))) short short8;
typedef __attribute__((ext_vector_type(4))) float f32x4;

__device__ __forceinline__ float sigmoidf_(float x){ return 1.f/(1.f+expf(-x)); }

__device__ __forceinline__ ushort f2b(float x){
  uint b = __builtin_bit_cast(uint, x);
  uint r = (b + 0x7FFFu + ((b>>16)&1u)) >> 16;
  return (ushort)r;
}
__device__ __forceinline__ uint pk2(float lo, float hi){
  return (uint)f2b(lo) | ((uint)f2b(hi)<<16);
}
// 4 bf16 (packed uint2) -> float4
__device__ __forceinline__ float4 b2f4(uint2 u){
  float4 f;
  f.x = __builtin_bit_cast(float, u.x<<16);
  f.y = __builtin_bit_cast(float, u.x & 0xffff0000u);
  f.z = __builtin_bit_cast(float, u.y<<16);
  f.w = __builtin_bit_cast(float, u.y & 0xffff0000u);
  return f;
}
// 8-lane sum (aligned 8-group): quad xor1, quad xor2, row_half_mirror
__device__ __forceinline__ float red8(float x){
  int t = __builtin_amdgcn_update_dpp(0, __builtin_bit_cast(int,x), 0xB1, 0xF, 0xF, true);
  x += __builtin_bit_cast(float,t);
  t = __builtin_amdgcn_update_dpp(0, __builtin_bit_cast(int,x), 0x4E, 0xF, 0xF, true);
  x += __builtin_bit_cast(float,t);
  t = __builtin_amdgcn_update_dpp(0, __builtin_bit_cast(int,x), 0x141, 0xF, 0xF, true);
  x += __builtin_bit_cast(float,t);
  return x;
}
__device__ __forceinline__ void gload16(const ushort* g, ushort* l){
  __builtin_amdgcn_global_load_lds((const __attribute__((address_space(1))) void*)g,
                                   (__attribute__((address_space(3))) void*)l, 16, 0, 0);
}

// ---------------- shared beta helper (128-thread LN blocks) ----------------
__device__ __forceinline__ void beta_from_row(
    int n, int tid, const float y0, const float y1, const float y2,
    const float* __restrict__ Wb, const float* __restrict__ bbv,
    const int* __restrict__ amask, float* __restrict__ Bb,
    float (*bred)[13])
{
  float part[12];
  #pragma unroll
  for (int hh=0;hh<12;hh++) part[hh]=0.f;
  #pragma unroll
  for (int j=0;j<3;j++){
    int d = tid + j*128;
    float yv = (j==0)?y0:(j==1)?y1:y2;
    const float* wrow = Wb + (long)d*12;
    #pragma unroll
    for (int hh=0;hh<12;hh++) part[hh] += yv * wrow[hh];
  }
  #pragma unroll
  for (int hh=0;hh<12;hh++) bred[tid][hh] = part[hh];
  __syncthreads();
  if (tid < 96){
    int hh = tid>>3, i = tid&7;
    float s = 0.f;
    #pragma unroll
    for (int k=0;k<16;k++) s += bred[i + 8*k][hh];
    s += __shfl_xor(s,1); s += __shfl_xor(s,2); s += __shfl_xor(s,4);
    if (i==0) Bb[(long)n*NHEAD+hh] = (float)amask[n] * sigmoidf_(s + bbv[hh]);
  }
}

// ---------------- embedding + LN (f32 + bf16 shadow) + beta(layer 0) -------------
__global__ __launch_bounds__(128) void embed_ln_kernel(
    const int* __restrict__ ids, const float* __restrict__ tok,
    const float* __restrict__ pos, const float* __restrict__ typ,
    const float* __restrict__ g, const float* __restrict__ bvec,
    float* __restrict__ out, ushort* __restrict__ outb,
    const float* __restrict__ Wb0, const float* __restrict__ bb0,
    const int* __restrict__ amask, float* __restrict__ Bb)
{
  __shared__ float r1[2], r2[2];
  __shared__ float bred[128][13];
  int n = blockIdx.x;
  int t = n & (SEQ-1);
  int id = ids[n];
  int tid = threadIdx.x;
  float v[3]; float s1=0.f, s2=0.f;
  #pragma unroll
  for (int j=0;j<3;j++){
    int d = tid + j*128;
    float x = tok[(long)id*DMODEL + d] + pos[t*DMODEL + d] + typ[d];
    v[j]=x; s1+=x; s2+=x*x;
  }
  #pragma unroll
  for (int m=1;m<64;m<<=1){ s1 += __shfl_xor(s1,m); s2 += __shfl_xor(s2,m); }
  if ((tid&63)==0){ r1[tid>>6]=s1; r2[tid>>6]=s2; }
  __syncthreads();
  s1 = r1[0]+r1[1]; s2 = r2[0]+r2[1];
  float mean = s1*(1.f/DMODEL);
  float var  = s2*(1.f/DMODEL) - mean*mean;
  float inv  = rsqrtf(var + 1e-12f);
  float y[3];
  #pragma unroll
  for (int j=0;j<3;j++){
    int d = tid + j*128;
    y[j] = (v[j]-mean)*inv*g[d] + bvec[d];
    out[(long)n*DMODEL + d] = y[j];
    outb[(long)n*DMODEL + d] = f2b(y[j]);
  }
  __syncthreads();
  beta_from_row(n, tid, y[0], y[1], y[2], Wb0, bb0, amask, Bb, bred);
}

// ---------------- residual add + LN (f32 + bf16 shadow) + optional beta ----------
__global__ __launch_bounds__(128) void add_ln_kernel(
    float* __restrict__ h, const float* __restrict__ res,
    const float* __restrict__ g, const float* __restrict__ bvec,
    ushort* __restrict__ hb,
    const float* __restrict__ Wbn, const float* __restrict__ bbn,
    const int* __restrict__ amask, float* __restrict__ Bb)
{
  __shared__ float r1[2], r2[2];
  __shared__ float bred[128][13];
  int n = blockIdx.x;
  int tid = threadIdx.x;
  float v[3]; float s1=0.f, s2=0.f;
  #pragma unroll
  for (int j=0;j<3;j++){
    int d = tid + j*128;
    float x = h[(long)n*DMODEL + d] + res[(long)n*DMODEL + d];
    v[j]=x; s1+=x; s2+=x*x;
  }
  #pragma unroll
  for (int m=1;m<64;m<<=1){ s1 += __shfl_xor(s1,m); s2 += __shfl_xor(s2,m); }
  if ((tid&63)==0){ r1[tid>>6]=s1; r2[tid>>6]=s2; }
  __syncthreads();
  s1 = r1[0]+r1[1]; s2 = r2[0]+r2[1];
  float mean = s1*(1.f/DMODEL);
  float var  = s2*(1.f/DMODEL) - mean*mean;
  float inv  = rsqrtf(var + 1e-12f);
  float y[3];
  #pragma unroll
  for (int j=0;j<3;j++){
    int d = tid + j*128;
    y[j] = (v[j]-mean)*inv*g[d] + bvec[d];
    h[(long)n*DMODEL + d] = y[j];
    hb[(long)n*DMODEL + d] = f2b(y[j]);
  }
  if (Wbn){
    __syncthreads();
    beta_from_row(n, tid, y[0], y[1], y[2], Wbn, bbn, amask, Bb, bred);
  }
}

// ---------------- ALL-layer weight transpose+convert (runs once) ----------------
__global__ __launch_bounds__(256) void tcvt6(
    const float* __restrict__ Wq, const float* __restrict__ Wk,
    const float* __restrict__ Wv, const float* __restrict__ Wg,
    const float* __restrict__ Wo, const float* __restrict__ W1,
    const float* __restrict__ W2, ushort* __restrict__ WTA)
{
  __shared__ float tile[32][33];
  int l = blockIdx.x / 1872;
  int bid = blockIdx.x % 1872;
  const float* Wq_l = Wq + (long)l*DMODEL*DMODEL;
  const float* Wk_l = Wk + (long)l*DMODEL*DMODEL;
  const float* Wv_l = Wv + (long)l*DMODEL*DMODEL;
  const float* Wg_l = Wg + (long)l*DMODEL*DMODEL;
  const float* Wo_l = Wo + (long)l*DMODEL*DMODEL;
  const float* W1_l = W1 + (long)l*DMODEL*DFF;
  const float* W2_l = W2 + (long)l*DFF*DMODEL;
  ushort* WTAl = WTA + (long)l*WTAL;

  const float* src; long dstbase; int rowlen, Nd, tk, tn, row0;
  if (bid < 720){
    int seg = bid/144, t = bid%144;
    tk = t%12; tn = t/12;
    src = (seg==0)?Wq_l:(seg==1)?Wk_l:(seg==2)?Wv_l:(seg==3)?Wg_l:Wo_l;
    Nd = 384; rowlen = 384;
    if (seg<4){ dstbase=0; row0=seg*384; }
    else      { dstbase=589824; row0=0; }
  } else if (bid < 1296){
    int t = bid-720; tk=t%12; tn=t/12;
    src=W1_l; Nd=DFF; dstbase=737280; row0=0; rowlen=384;
  } else {
    int t = bid-1296; tk=t%48; tn=t/48;
    src=W2_l; Nd=384; dstbase=1327104; row0=0; rowlen=DFF;
  }
  int k0=tk*32, n0=tn*32;
  int tt=threadIdx.x;
  int r=tt>>3, c4=(tt&7)<<2;
  const float* sp = src + (long)(k0+r)*Nd + n0 + c4;
  float4 f = *(const float4*)sp;
  tile[r][c4+0]=f.x; tile[r][c4+1]=f.y; tile[r][c4+2]=f.z; tile[r][c4+3]=f.w;
  __syncthreads();
  ushort4 o;
  o.x=f2b(tile[c4+0][r]); o.y=f2b(tile[c4+1][r]);
  o.z=f2b(tile[c4+2][r]); o.w=f2b(tile[c4+3][r]);
  *(ushort4*)(WTAl + dstbase + (long)(row0+n0+r)*rowlen + k0 + c4) = o;
}

// XCD-aware swizzle: grid (64, ny), total %8==0. Returns (bx,by).
__device__ __forceinline__ int2 xcd_swz(){
  int lin = blockIdx.y*64 + blockIdx.x;
  int nb = gridDim.x*gridDim.y;
  int s = (lin & 7)*(nb>>3) + (lin>>3);
  return make_int2(s & 63, s >> 6);
}

// ---------------- bf16 MFMA GEMM, 128x128 tile, BK=32 ----------------
template<int ACT, int OUTBF>
__global__ __launch_bounds__(256) void gemm_bf(
    const ushort* __restrict__ Xb, const ushort* __restrict__ WT,
    const float* __restrict__ bias, void* __restrict__ Cv, int Kd, int Nd)
{
  __shared__ ushort A_lds[128*32];
  __shared__ ushort B_lds[128*32];
  int tid = threadIdx.x;
  int2 bxy = xcd_swz();
  int bm = bxy.x*128, bn = bxy.y*128;
  int w = tid>>6, lane = tid&63;
  int wm = w>>1, wn = w&1;
  f32x4 acc[4][4];
  #pragma unroll
  for (int i=0;i<4;i++)
    #pragma unroll
    for (int j=0;j<4;j++) acc[i][j]=(f32x4)(0.f);

  int cl = lane&15, koff = (lane>>4)*8;
  int srow = w*32 + (lane>>2);
  int scol = (lane&3)*8;
  const ushort* gA0 = Xb + (long)(bm+srow)*Kd + scol;
  const ushort* gA1 = gA0 + 16*(long)Kd;
  const ushort* gB0 = WT + (long)(bn+srow)*Kd + scol;
  const ushort* gB1 = gB0 + 16*(long)Kd;
  ushort* lA = A_lds + w*1024;
  ushort* lB = B_lds + w*1024;

  for (int k0=0; k0<Kd; k0+=32){
    gload16(gA0+k0, lA);
    gload16(gA1+k0, lA+512);
    gload16(gB0+k0, lB);
    gload16(gB1+k0, lB+512);
    __syncthreads();
    short8 bf[4];
    #pragma unroll
    for (int ni=0;ni<4;ni++)
      bf[ni] = *(const short8*)&B_lds[(wn*64+ni*16+cl)*32 + koff];
    #pragma unroll
    for (int mi=0;mi<4;mi++){
      short8 af = *(const short8*)&A_lds[(wm*64+mi*16+cl)*32 + koff];
      #pragma unroll
      for (int ni=0;ni<4;ni++)
        acc[mi][ni] = __builtin_amdgcn_mfma_f32_16x16x32_bf16(af, bf[ni], acc[mi][ni], 0,0,0);
    }
    __syncthreads();
  }

  int rb = (lane>>4)*4;
  #pragma unroll
  for (int ni=0; ni<4; ni++){
    int col = bn + wn*64 + ni*16 + cl;
    float bsv = bias ? bias[col] : 0.f;
    #pragma unroll
    for (int mi=0; mi<4; mi++){
      #pragma unroll
      for (int j=0;j<4;j++){
        int row = bm + wm*64 + mi*16 + rb + j;
        float c = acc[mi][ni][j] + bsv;
        if (ACT==1)      c = c*sigmoidf_(c);
        else if (ACT==2) c = 0.5f*c*(1.f+erff(c*0.70710678118f));
        else if (ACT==3) c = sigmoidf_(c);
        if (OUTBF) ((ushort*)Cv)[(long)row*Nd + col] = f2b(c);
        else       ((float*)Cv)[(long)row*Nd + col] = c;
      }
    }
  }
}

// ---------------- bf16 MFMA GEMM, 128x64 tile, BK=32 ----------------
template<int ACT, int OUTBF>
__global__ __launch_bounds__(256) void gemm_bf2(
    const ushort* __restrict__ Xb, const ushort* __restrict__ WT,
    const float* __restrict__ bias, void* __restrict__ Cv, int Kd, int Nd)
{
  __shared__ ushort A_lds[128*32];
  __shared__ ushort B_lds[64*32];
  int tid = threadIdx.x;
  int2 bxy = xcd_swz();
  int bm = bxy.x*128, bn = bxy.y*64;
  int w = tid>>6, lane = tid&63;
  int wm = w>>1, wn = w&1;
  f32x4 acc[4][2];
  #pragma unroll
  for (int i=0;i<4;i++){ acc[i][0]=(f32x4)(0.f); acc[i][1]=(f32x4)(0.f); }

  int cl = lane&15, koff = (lane>>4)*8;
  int srowA = w*32 + (lane>>2);
  int scol = (lane&3)*8;
  const ushort* gA0 = Xb + (long)(bm+srowA)*Kd + scol;
  const ushort* gA1 = gA0 + 16*(long)Kd;
  int srowB = w*16 + (lane>>2);
  const ushort* gB = WT + (long)(bn+srowB)*Kd + scol;
  ushort* lA = A_lds + w*1024;
  ushort* lB = B_lds + w*512;

  for (int k0=0; k0<Kd; k0+=32){
    gload16(gA0+k0, lA);
    gload16(gA1+k0, lA+512);
    gload16(gB+k0, lB);
    __syncthreads();
    short8 b0 = *(const short8*)&B_lds[(wn*32+cl)*32 + koff];
    short8 b1 = *(const short8*)&B_lds[(wn*32+16+cl)*32 + koff];
    #pragma unroll
    for (int mi=0;mi<4;mi++){
      short8 af = *(const short8*)&A_lds[(wm*64+mi*16+cl)*32 + koff];
      acc[mi][0] = __builtin_amdgcn_mfma_f32_16x16x32_bf16(af, b0, acc[mi][0], 0,0,0);
      acc[mi][1] = __builtin_amdgcn_mfma_f32_16x16x32_bf16(af, b1, acc[mi][1], 0,0,0);
    }
    __syncthreads();
  }

  int rb = (lane>>4)*4;
  #pragma unroll
  for (int ni=0; ni<2; ni++){
    int col = bn + wn*32 + ni*16 + cl;
    float bsv = bias ? bias[col] : 0.f;
    #pragma unroll
    for (int mi=0; mi<4; mi++){
      #pragma unroll
      for (int j=0;j<4;j++){
        int row = bm + wm*64 + mi*16 + rb + j;
        float c = acc[mi][ni][j] + bsv;
        if (ACT==1)      c = c*sigmoidf_(c);
        else if (ACT==2) c = 0.5f*c*(1.f+erff(c*0.70710678118f));
        else if (ACT==3) c = sigmoidf_(c);
        if (OUTBF) ((ushort*)Cv)[(long)row*Nd + col] = f2b(c);
        else       ((float*)Cv)[(long)row*Nd + col] = c;
      }
    }
  }
}

// ---------------- fused QKVG GEMM, BK=32, bf16 output ----------------
__global__ __launch_bounds__(256) void gemm_qkvg(
    const ushort* __restrict__ Xb, const ushort* __restrict__ WT,
    const float* __restrict__ bq, const float* __restrict__ bk,
    const float* __restrict__ bv, ushort* __restrict__ C)
{
  __shared__ ushort A_lds[128*32];
  __shared__ ushort B_lds[128*32];
  int tid = threadIdx.x;
  int2 bxy = xcd_swz();
  int bm = bxy.x*128, bn = bxy.y*128;
  int w = tid>>6, lane = tid&63;
  int wm = w>>1, wn = w&1;
  f32x4 acc[4][4];
  #pragma unroll
  for (int i=0;i<4;i++)
    #pragma unroll
    for (int j=0;j<4;j++) acc[i][j]=(f32x4)(0.f);

  int cl = lane&15, koff = (lane>>4)*8;
  int srow = w*32 + (lane>>2);
  int scol = (lane&3)*8;
  const ushort* gA0 = Xb + (long)(bm+srow)*DMODEL + scol;
  const ushort* gA1 = gA0 + 16*DMODEL;
  const ushort* gB0 = WT + (long)(bn+srow)*DMODEL + scol;
  const ushort* gB1 = gB0 + 16*DMODEL;
  ushort* lA = A_lds + w*1024;
  ushort* lB = B_lds + w*1024;

  for (int k0=0; k0<DMODEL; k0+=32){
    gload16(gA0+k0, lA);
    gload16(gA1+k0, lA+512);
    gload16(gB0+k0, lB);
    gload16(gB1+k0, lB+512);
    __syncthreads();
    short8 bf[4];
    #pragma unroll
    for (int ni=0;ni<4;ni++)
      bf[ni] = *(const short8*)&B_lds[(wn*64+ni*16+cl)*32 + koff];
    #pragma unroll
    for (int mi=0;mi<4;mi++){
      short8 af = *(const short8*)&A_lds[(wm*64+mi*16+cl)*32 + koff];
      #pragma unroll
      for (int ni=0;ni<4;ni++)
        acc[mi][ni] = __builtin_amdgcn_mfma_f32_16x16x32_bf16(af, bf[ni], acc[mi][ni], 0,0,0);
    }
    __syncthreads();
  }

  int seg = bxy.y/3;
  const float* bp = (seg==0)?bq:(seg==1)?bk:(seg==2)?bv:nullptr;
  int boff = seg*384;
  int rb = (lane>>4)*4;
  #pragma unroll
  for (int ni=0; ni<4; ni++){
    int col = bn + wn*64 + ni*16 + cl;
    float bsv = bp ? bp[col-boff] : 0.f;
    #pragma unroll
    for (int mi=0; mi<4; mi++){
      #pragma unroll
      for (int j=0;j<4;j++){
        int row = bm + wm*64 + mi*16 + rb + j;
        float c = acc[mi][ni][j] + bsv;
        if (seg<2)       c = c*sigmoidf_(c);
        else if (seg==3) c = sigmoidf_(c);
        C[(long)row*DFF + col] = f2b(c);
      }
    }
  }
}

// ---------------- delta-rule scan v12 (best measured): 512 thr, f32 LDS ----------
// 192 blocks = (b,h); 512 thr = 8 waves: st = w>>2, vq = w&3.
// lane: kq = lane&7 (k = kq*4..+3), v = vq*8 + (lane>>3). S[4] in regs.
// TCH=64 single LDS f32 buffer + reg-staged next chunk (sched_barrier-pinned);
// staging converts bf16->f32 and fuses knorm; V transposed [v][t]; k/q 3-deep
// register pipeline (pads rows 64/65); v/beta per-4 group ping-pong prefetch.
__global__ __launch_bounds__(512,2) void scan12_kernel(
    const ushort* __restrict__ QKVGb, const float* __restrict__ Bb,
    const float* __restrict__ dfl, const float* __restrict__ dsl,
    const float* __restrict__ mixl, ushort* __restrict__ OA)
{
  __shared__ float Qc[66][36], Kc[66][36], Vt[32][68], Bc[68], Ofs[2][64][36];
  int bh = blockIdx.x;
  int b = bh / NHEAD, hh = bh - b*NHEAD;
  int tid = threadIdx.x;
  int w = tid>>6, lane = tid&63;
  int st = w>>2, vq = w&3;
  int kq = lane&7, v = vq*8 + (lane>>3);
  float dec = sigmoidf_(st ? dsl[hh] : dfl[hh]);
  float mix = sigmoidf_(mixl[hh]);
  long rowbase = (long)b*SEQ;
  const ushort* rp = QKVGb + rowbase*DFF + hh*32;
  const float* bp = Bb + rowbase*NHEAD + hh;

  int r0 = tid>>3, c40 = (tid&7)<<2;
  float S[4] = {0.f,0.f,0.f,0.f};

  float4 sq, sk, sv; float sb = 0.f;
  {
    long g = (long)r0*DFF;
    sq = b2f4(*(const uint2*)(rp + g + c40));
    sk = b2f4(*(const uint2*)(rp + g + 384 + c40));
    sv = b2f4(*(const uint2*)(rp + g + 768 + c40));
    if (tid < 64) sb = bp[(long)tid*NHEAD];
    float ss = red8(sk.x*sk.x + sk.y*sk.y + sk.z*sk.z + sk.w*sk.w);
    float inv = 1.f/(sqrtf(ss)+1e-6f);
    sk.x*=inv; sk.y*=inv; sk.z*=inv; sk.w*=inv;
    *(float4*)&Qc[r0][c40] = sq;
    *(float4*)&Kc[r0][c40] = sk;
    Vt[c40+0][r0]=sv.x; Vt[c40+1][r0]=sv.y; Vt[c40+2][r0]=sv.z; Vt[c40+3][r0]=sv.w;
    if (tid < 64) Bc[tid] = sb;
  }
  __syncthreads();

  for (int c=0; c<8; ++c){
    if (c < 7){
      long g = (long)((c+1)*64 + r0)*DFF;
      sq = b2f4(*(const uint2*)(rp + g + c40));
      sk = b2f4(*(const uint2*)(rp + g + 384 + c40));
      sv = b2f4(*(const uint2*)(rp + g + 768 + c40));
      if (tid < 64) sb = bp[(long)((c+1)*64 + tid)*NHEAD];
    }
    float4 g4 = b2f4(*(const uint2*)(rp + (long)(c*64 + r0)*DFF + 1152 + c40));
    __builtin_amdgcn_sched_barrier(0);   // pin load issue before inner loop

    // ---- 64 steps: 3-deep k/q pipeline + ping-pong v/beta groups
    float4 kA = *(const float4*)&Kc[0][kq*4];
    float4 qA = *(const float4*)&Qc[0][kq*4];
    float4 kB = *(const float4*)&Kc[1][kq*4];
    float4 qB = *(const float4*)&Qc[1][kq*4];
    float vrA[4], brA[4], vrB[4], brB[4];
    *(float4*)vrA = *(const float4*)&Vt[v][0];
    *(float4*)brA = *(const float4*)&Bc[0];

    for (int t8=0; t8<8; ++t8){
      *(float4*)vrB = *(const float4*)&Vt[v][(2*t8+1)*4];
      *(float4*)brB = *(const float4*)&Bc[(2*t8+1)*4];
      #pragma unroll
      for (int i=0;i<4;i++){
        int t = t8*8 + i;
        float4 kN = *(const float4*)&Kc[t+2][kq*4];
        float4 qN = *(const float4*)&Qc[t+2][kq*4];
        float pa = kA.x*S[0] + kA.y*S[1];
        float pb = kA.z*S[2] + kA.w*S[3];
        float p = red8(pa+pb);
        float err = (vrA[i] - p)*brA[i];
        S[0] = dec*S[0] + kA.x*err;
        S[1] = dec*S[1] + kA.y*err;
        S[2] = dec*S[2] + kA.z*err;
        S[3] = dec*S[3] + kA.w*err;
        float oa = qA.x*S[0] + qA.y*S[1];
        float ob = qA.z*S[2] + qA.w*S[3];
        float o = red8(oa+ob);
        if (kq==0) Ofs[st][t][v] = o;
        kA=kB; qA=qB; kB=kN; qB=qN;
      }
      *(float4*)vrA = *(const float4*)&Vt[v][(2*t8+2)*4];
      *(float4*)brA = *(const float4*)&Bc[(2*t8+2)*4];
      #pragma unroll
      for (int i=0;i<4;i++){
        int t = t8*8 + 4 + i;
        float4 kN = *(const float4*)&Kc[t+2][kq*4];   // rows 64/65 = pad
        float4 qN = *(const float4*)&Qc[t+2][kq*4];
        float pa = kA.x*S[0] + kA.y*S[1];
        float pb = kA.z*S[2] + kA.w*S[3];
        float p = red8(pa+pb);
        float err = (vrB[i] - p)*brB[i];
        S[0] = dec*S[0] + kA.x*err;
        S[1] = dec*S[1] + kA.y*err;
        S[2] = dec*S[2] + kA.z*err;
        S[3] = dec*S[3] + kA.w*err;
        float oa = qA.x*S[0] + qA.y*S[1];
        float ob = qA.z*S[2] + qA.w*S[3];
        float o = red8(oa+ob);
        if (kq==0) Ofs[st][t][v] = o;
        kA=kB; qA=qB; kB=kN; qB=qN;
      }
    }
    __syncthreads();

    // ---- epilogue (mix+gate+bf16 out) + write staged next chunk
    {
      float4 of = *(const float4*)&Ofs[0][r0][c40];
      float4 os = *(const float4*)&Ofs[1][r0][c40];
      float a0 = (mix*of.x + (1.f-mix)*os.x)*g4.x;
      float a1 = (mix*of.y + (1.f-mix)*os.y)*g4.y;
      float a2 = (mix*of.z + (1.f-mix)*os.z)*g4.z;
      float a3 = (mix*of.w + (1.f-mix)*os.w)*g4.w;
      uint2 o2; o2.x = pk2(a0,a1); o2.y = pk2(a2,a3);
      *(uint2*)(OA + (rowbase + c*64 + r0)*DMODEL + hh*32 + c40) = o2;
    }
    if (c < 7){
      *(float4*)&Qc[r0][c40] = sq;
      *(float4*)&Kc[r0][c40] = sk;
      Vt[c40+0][r0]=sv.x; Vt[c40+1][r0]=sv.y; Vt[c40+2][r0]=sv.z; Vt[c40+3][r0]=sv.w;
      if (tid < 64) Bc[tid] = sb;
    }
    __syncthreads();
  }
}

// ---------------- masked mean pool + L2 normalize ----------------
__global__ __launch_bounds__(384) void pool_norm_kernel(
    const float* __restrict__ h, const int* __restrict__ mask, float* __restrict__ out)
{
  int b = blockIdx.x; int d = threadIdx.x;
  float s=0.f, ms=0.f;
  for (int t=0;t<SEQ;t++){
    float m = (float)mask[b*SEQ+t];
    s += h[((long)b*SEQ+t)*DMODEL + d]*m;
    ms += m;
  }
  float emb = s / fmaxf(ms, 1e-9f);
  float ss = emb*emb;
  #pragma unroll
  for (int m2=1;m2<64;m2<<=1) ss += __shfl_xor(ss,m2);
  __shared__ float r[6];
  if ((d&63)==0) r[d>>6]=ss;
  __syncthreads();
  ss = r[0]+r[1]+r[2]+r[3]+r[4]+r[5];
  out[b*DMODEL+d] = emb / (sqrtf(ss)+1e-12f);
}

extern "C" void kernel_launch(void* const* d_in, const int* in_sizes, int n_in,
                              void* d_out, int out_size, void* d_ws, size_t ws_size,
                              hipStream_t stream)
{
  const int*   ids   = (const int*)d_in[0];
  const int*   amask = (const int*)d_in[1];
  const float* etok  = (const float*)d_in[2];
  const float* epos  = (const float*)d_in[3];
  const float* etyp  = (const float*)d_in[4];
  const float* elng  = (const float*)d_in[5];
  const float* elnb  = (const float*)d_in[6];
  const float* Wq = (const float*)d_in[7];  const float* bq = (const float*)d_in[8];
  const float* Wk = (const float*)d_in[9];  const float* bk = (const float*)d_in[10];
  const float* Wv = (const float*)d_in[11]; const float* bv = (const float*)d_in[12];
  const float* Wb = (const float*)d_in[13]; const float* bb = (const float*)d_in[14];
  const float* dfl = (const float*)d_in[15];
  const float* dsl = (const float*)d_in[16];
  const float* mixl= (const float*)d_in[17];
  const float* Wg = (const float*)d_in[18];
  const float* Wo = (const float*)d_in[19]; const float* bo = (const float*)d_in[20];
  const float* alng = (const float*)d_in[21]; const float* alnb = (const float*)d_in[22];
  const float* W1 = (const float*)d_in[23]; const float* b1 = (const float*)d_in[24];
  const float* W2 = (const float*)d_in[25]; const float* b2 = (const float*)d_in[26];
  const float* flng = (const float*)d_in[27]; const float* flnb = (const float*)d_in[28];

  float* ws = (float*)d_ws;
  const long TD = (long)NTOK*DMODEL;
  float* h      = ws;                              // [8192][384] f32
  ushort* hbf   = (ushort*)(h + TD);               // [8192][384] bf16
  ushort* QKVGb = (ushort*)(h + TD + TD/2);        // [8192][1536] bf16 (2*TD floats)
  ushort* OA    = (ushort*)(h + TD + TD/2 + 2*TD); // [8192][384] bf16
  float* Rb     = h + TD + TD/2 + 2*TD + TD/2;     // attn/ffn output f32
  float* Bb     = Rb + TD;                         // [8192][12]
  ushort* WTA   = (ushort*)(Bb + (long)NTOK*NHEAD);// 6 layers x WTAL ushorts
  ushort* F1B   = QKVGb;                           // FFN mid bf16, aliases dead QKVGb

  embed_ln_kernel<<<NTOK,128,0,stream>>>(ids, etok, epos, etyp, elng, elnb, h, hbf,
                                         Wb, bb, amask, Bb);
  tcvt6<<<6*1872,256,0,stream>>>(Wq, Wk, Wv, Wg, Wo, W1, W2, WTA);

  for (int l=0;l<NLAYER;l++){
    ushort* WTAl = WTA + (long)l*WTAL;
    gemm_qkvg<<<dim3(64,12),256,0,stream>>>(hbf, WTAl, bq+l*DMODEL, bk+l*DMODEL, bv+l*DMODEL, QKVGb);
    scan12_kernel<<<BATCH*NHEAD,512,0,stream>>>(QKVGb, Bb, dfl + l*NHEAD, dsl + l*NHEAD, mixl + l*NHEAD, OA);
    gemm_bf2<0,0><<<dim3(64,6),256,0,stream>>>(OA, WTAl+589824, bo + l*DMODEL, Rb, DMODEL, DMODEL);
    add_ln_kernel<<<NTOK,128,0,stream>>>(h, Rb, alng + (long)l*DMODEL, alnb + (long)l*DMODEL, hbf,
                                         nullptr, nullptr, amask, Bb);
    gemm_bf<2,1><<<dim3(64,12),256,0,stream>>>(hbf, WTAl+737280, b1 + (long)l*DFF, F1B, DMODEL, DFF);
    gemm_bf2<0,0><<<dim3(64,6),256,0,stream>>>(F1B, WTAl+1327104, b2 + (long)l*DMODEL, Rb, DFF, DMODEL);
    const float* Wbn = (l+1<NLAYER) ? (Wb + (long)(l+1)*DMODEL*NHEAD) : nullptr;
    const float* bbn = (l+1<NLAYER) ? (bb + (long)(l+1)*NHEAD) : nullptr;
    add_ln_kernel<<<NTOK,128,0,stream>>>(h, Rb, flng + (long)l*DMODEL, flnb + (long)l*DMODEL, hbf,
                                         Wbn, bbn, amask, Bb);
  }

  pool_norm_kernel<<<BATCH,384,0,stream>>>(h, amask, (float*)d_out);
}